// Round 5
// baseline (104.367 us; speedup 1.0000x reference)
//
#include <hip/hip_runtime.h>
#include <math.h>

// KANConv2D via bf16 MFMA 32x32x16, R5: single fused kernel.
// - No cvt kernel, no d_ws: fp32 weights loaded directly as MFMA B-frags
//   (8 consecutive floats/lane = 32 B; per step the wave reads 32 aligned
//   64-B lines -> zero L2 amplification) and packed to bf16 in-register
//   (round-half-up + v_perm_b32).
// - Otherwise R3/R4 structure: 392 blocks (4 b x 14 x 7 tiles of 4x8 px,
//   M=32), 256 thr = 4 waves = (nf oc-half) x (kh2 K-half), K-split
//   reduced via LDS at the end.
// Frag convention (A and B consistent): lane&31 = m/n; k = (lane>>5)*8 + j
// within each k16 step. C/D: col=lane&31=n, row=(reg&3)+8*(reg>>2)+4*(lane>>5).

typedef __attribute__((ext_vector_type(8)))  short bf16x8;
typedef __attribute__((ext_vector_type(4)))  float f32x4;
typedef __attribute__((ext_vector_type(16))) float f32x16;

#define MFMA32(a, b, c) __builtin_amdgcn_mfma_f32_32x32x16_bf16((a), (b), (c), 0, 0, 0)

__device__ __forceinline__ unsigned short f2bf(float f) {
    unsigned u = __builtin_bit_cast(unsigned, f);
    u = (u + 0x7fffu + ((u >> 16) & 1u)) >> 16;   // RNE
    return (unsigned short)u;
}

// pack 8 fp32 -> 8 bf16 (round-half-up: +0x8000 then take high 16 bits)
__device__ __forceinline__ bf16x8 pack8(float4 a, float4 b) {
    unsigned x0 = __builtin_bit_cast(unsigned, a.x) + 0x8000u;
    unsigned x1 = __builtin_bit_cast(unsigned, a.y) + 0x8000u;
    unsigned x2 = __builtin_bit_cast(unsigned, a.z) + 0x8000u;
    unsigned x3 = __builtin_bit_cast(unsigned, a.w) + 0x8000u;
    unsigned x4 = __builtin_bit_cast(unsigned, b.x) + 0x8000u;
    unsigned x5 = __builtin_bit_cast(unsigned, b.y) + 0x8000u;
    unsigned x6 = __builtin_bit_cast(unsigned, b.z) + 0x8000u;
    unsigned x7 = __builtin_bit_cast(unsigned, b.w) + 0x8000u;
    union { unsigned i[4]; bf16x8 v; } r;
    r.i[0] = __builtin_amdgcn_perm(x1, x0, 0x07060302u);  // hi16(x1):hi16(x0)
    r.i[1] = __builtin_amdgcn_perm(x3, x2, 0x07060302u);
    r.i[2] = __builtin_amdgcn_perm(x5, x4, 0x07060302u);
    r.i[3] = __builtin_amdgcn_perm(x7, x6, 0x07060302u);
    return r.v;
}

__device__ __forceinline__ void eval_bases(float v, float bs[8]) {
    #pragma unroll
    for (int i = 0; i < 8; ++i) bs[i] = 0.0f;
    // knots: t_g = (g-3)*0.4 - 1, support [-2.2, 2.2)
    float t = (v + 2.2f) * 2.5f;
    if (t >= 0.0f && t < 11.0f) {
        int j = (int)t;
        if (j > 10) j = 10;
        float knot = (float)(j - 3) * 0.4f - 1.0f;
        float u  = (v - knot) * 2.5f;
        float um = 1.0f - u;
        float u2 = u * u, u3 = u2 * u;
        const float s6 = 1.0f / 6.0f;
        float w0 = um * um * um * s6;
        float w1 = (3.0f * u3 - 6.0f * u2 + 4.0f) * s6;
        float w2 = (-3.0f * u3 + 3.0f * u2 + 3.0f * u + 1.0f) * s6;
        float w3 = u3 * s6;
        int i0 = j - 3;
        if (i0 >= 0)               bs[i0]     = w0;
        if (i0 + 1 >= 0 && i0 < 7) bs[i0 + 1] = w1;
        if (i0 + 2 >= 0 && i0 < 6) bs[i0 + 2] = w2;
        if (i0 + 3 <= 7)           bs[i0 + 3] = w3;
    }
}

__global__ __launch_bounds__(256, 3)
void kan_fused_kernel(const float* __restrict__ x,
                      const float* __restrict__ wb,
                      const float* __restrict__ ws,
                      const float* __restrict__ sc,
                      float* __restrict__ out) {
    __shared__ unsigned short smem[24832];   // 49664 B -> 3 blocks/CU
    unsigned short* sb    = smem;            // [32][60][8] = 15360 ushorts
    unsigned short* patch = smem + 15360;    // [32][296]   = 9472 ushorts

    const int tid = threadIdx.x;
    const int bx  = blockIdx.x;              // 0..391
    const int b   = bx / 98;
    const int r   = bx - b * 98;
    const int ty  = r / 7;
    const int tx  = r - ty * 7;
    const int h0  = ty * 4, w0 = tx * 8;

    const int lane = tid & 63;
    const int wv   = tid >> 6;        // 0..3
    const int nf   = wv & 1;          // oc half
    const int kh2  = wv >> 1;         // K half
    const int m    = lane & 31;       // A row = pixel
    const int kg   = lane >> 5;       // k-group within k16 step
    const int py0  = m >> 3, px0 = m & 7;
    const int ocl  = nf * 32 + m;     // this lane's B out-channel

    // fp32 B-frag base pointers (8 consecutive floats per lane per step)
    const float* bp32  = ws + ocl * 2304 + kh2 * 1152 + kg * 8;
    const float* wbp32 = wb + ocl * 288  + kh2 * 144  + kg * 8;

    // spline A offsets (ushort units): step s = kh2*72+g*9+u reads p = 2s+kg
    int aoff[9];
    #pragma unroll
    for (int u = 0; u < 9; ++u) {
        int t2  = 2 * u + kg;         // 0..17
        int dc  = t2 / 9;
        int tap = t2 - dc * 9;
        int kh  = tap / 3;
        int kw  = tap - kh * 3;
        aoff[u] = (dc * 60 + (py0 + kh) * 10 + (px0 + kw)) * 8;
    }

    // ---- phase 1: batch 8 independent x loads, then eval + store + scatter ----
    float vv[8];
    #pragma unroll
    for (int j = 0; j < 8; ++j) {
        int i = tid + j * 256;        // 0..2047
        float val = 0.0f;
        if (i < 1920) {
            int c  = i / 60;
            int hp = i - c * 60;
            int hy = hp / 10;
            int hx = hp - hy * 10;
            int hh = h0 + hy - 1, ww = w0 + hx - 1;
            if ((unsigned)hh < 56u && (unsigned)ww < 56u)
                val = x[((b * 32 + c) * 56 + hh) * 56 + ww];
        }
        vv[j] = val;
    }
    #pragma unroll
    for (int j = 0; j < 8; ++j) {
        int i = tid + j * 256;
        if (i < 1920) {
            int c  = i / 60;
            int hp = i - c * 60;
            int hy = hp / 10;
            int hx = hp - hy * 10;
            float bs[8];
            eval_bases(vv[j], bs);
            bf16x8 pk;
            #pragma unroll
            for (int j2 = 0; j2 < 8; ++j2) pk[j2] = (short)f2bf(bs[j2]);
            *reinterpret_cast<bf16x8*>(&sb[i * 8]) = pk;
            // scatter x into patch: halo (hy,hx) -> m=(hy-kh, hx-kw), k=c*9+kh*3+kw
            unsigned short xb = f2bf(vv[j]);
            #pragma unroll
            for (int kh = 0; kh < 3; ++kh) {
                int py = hy - kh;
                if ((unsigned)py < 4u) {
                    #pragma unroll
                    for (int kw = 0; kw < 3; ++kw) {
                        int px = hx - kw;
                        if ((unsigned)px < 8u)
                            patch[(py * 8 + px) * 296 + c * 9 + kh * 3 + kw] = xb;
                    }
                }
            }
        }
    }
    __syncthreads();

    // ---- spline GEMM: 72 k16-steps; B loaded fp32 + packed in-register ----
    f32x16 acc, accB;
    #pragma unroll
    for (int i = 0; i < 16; ++i) { acc[i] = 0.f; accB[i] = 0.f; }

    int cbase = kh2 * 7680;           // (16*kh2) channels * 480 ushorts
    for (int g = 0; g < 8; ++g) {
        #pragma unroll
        for (int u = 0; u < 9; ++u) {
            const float* p = bp32 + (g * 9 + u) * 16;
            float4 f0 = *reinterpret_cast<const float4*>(p);
            float4 f1 = *reinterpret_cast<const float4*>(p + 4);
            bf16x8 a = *reinterpret_cast<const bf16x8*>(&sb[cbase + aoff[u]]);
            acc = MFMA32(a, pack8(f0, f1), acc);
        }
        cbase += 960;
    }

    // ---- base GEMM: 9 k16-steps ----
    {
        const unsigned short* ap = &patch[m * 296 + kh2 * 144 + kg * 8];
        #pragma unroll
        for (int s = 0; s < 9; ++s) {
            const float* p = wbp32 + s * 16;
            float4 f0 = *reinterpret_cast<const float4*>(p);
            float4 f1 = *reinterpret_cast<const float4*>(p + 4);
            bf16x8 a = *reinterpret_cast<const bf16x8*>(ap + s * 16);
            accB = MFMA32(a, pack8(f0, f1), accB);
        }
    }

    // ---- K-split reduction: waves 2,3 -> waves 0,1 via LDS ----
    __syncthreads();
    float* red = (float*)smem;        // [2][64][36] floats = 18432 B
    if (kh2 == 1) {
        float* dst = red + (nf * 64 + lane) * 36;
        #pragma unroll
        for (int rq = 0; rq < 4; ++rq) {
            f32x4 vS, vB;
            #pragma unroll
            for (int rr = 0; rr < 4; ++rr) { vS[rr] = acc[rq*4+rr]; vB[rr] = accB[rq*4+rr]; }
            *reinterpret_cast<f32x4*>(dst + rq * 4)      = vS;
            *reinterpret_cast<f32x4*>(dst + 16 + rq * 4) = vB;
        }
    }
    __syncthreads();

    if (kh2 == 0) {
        const float* src = red + (nf * 64 + lane) * 36;
        #pragma unroll
        for (int rq = 0; rq < 4; ++rq) {
            f32x4 vS = *reinterpret_cast<const f32x4*>(src + rq * 4);
            f32x4 vB = *reinterpret_cast<const f32x4*>(src + 16 + rq * 4);
            #pragma unroll
            for (int rr = 0; rr < 4; ++rr) { acc[rq*4+rr] += vS[rr]; accB[rq*4+rr] += vB[rr]; }
        }
        // ---- epilogue: py = reg&3 (rq), px = 4*kg + rr-from-store; row=(reg&3)+4*kg ----
        const int oc  = nf * 32 + m;
        const float scv = sc[oc];
        float* ob = out + ((b * 64 + oc) * 56 + h0) * 56 + w0 + 4 * kg;
        #pragma unroll
        for (int rq = 0; rq < 4; ++rq) {
            f32x4 res;
            #pragma unroll
            for (int rr = 0; rr < 4; ++rr) {
                float bv = accB[rq * 4 + rr];
                float si = bv / (1.0f + __expf(-bv));
                res[rr] = si + scv * acc[rq * 4 + rr];
            }
            *reinterpret_cast<f32x4*>(ob + rq * 56) = res;
        }
    }
}

extern "C" void kernel_launch(void* const* d_in, const int* in_sizes, int n_in,
                              void* d_out, int out_size, void* d_ws, size_t ws_size,
                              hipStream_t stream) {
    const float* x  = (const float*)d_in[0];   // (4,32,56,56)
    const float* wb = (const float*)d_in[1];   // (64,32,3,3)
    const float* ws = (const float*)d_in[2];   // (64,288,8)
    const float* sc = (const float*)d_in[3];   // (64,)
    float* out = (float*)d_out;                // (4,64,56,56)

    kan_fused_kernel<<<392, 256, 0, stream>>>(x, wb, ws, sc, out);
}

// Round 6
// 78.107 us; speedup vs baseline: 1.3362x; 1.3362x over previous
//
#include <hip/hip_runtime.h>
#include <math.h>

// KANConv2D via bf16 MFMA 16x16x32, R6.
// - cvt kernel pre-swizzles fp32 weights -> bf16 MFMA B-frag streams in d_ws
//   (d_ws poison cost is fixed harness overhead; using it is free).
// - Main: 392 blocks (4 b x 14x7 tiles of 4x8 px, M=32), 512 thr = 8 waves:
//   wave = (nq 0..3: oc quarter of 16) x (mh 0..1: M half of 16 rows).
//   NO K-split -> no cross-wave reduction, single barrier, acc = 4+4 VGPRs.
// Frag maps (validated by passing R1 kernel / m89/m120):
//   A: m = lane&15, k = (lane>>4)*8 + j   B: n = lane&15, k = (lane>>4)*8 + j
//   C/D: col = lane&15 = n, row = (lane>>4)*4 + reg = m.

typedef __attribute__((ext_vector_type(8))) short bf16x8;
typedef __attribute__((ext_vector_type(4))) float f32x4;

#define MFMA16(a, b, c) __builtin_amdgcn_mfma_f32_16x16x32_bf16((a), (b), (c), 0, 0, 0)

__device__ __forceinline__ unsigned short f2bf(float f) {
    unsigned u = __builtin_bit_cast(unsigned, f);
    u = (u + 0x7fffu + ((u >> 16) & 1u)) >> 16;   // RNE
    return (unsigned short)u;
}

__device__ __forceinline__ void eval_bases(float v, float bs[8]) {
    #pragma unroll
    for (int i = 0; i < 8; ++i) bs[i] = 0.0f;
    // knots: t_g = (g-3)*0.4 - 1, support [-2.2, 2.2)
    float t = (v + 2.2f) * 2.5f;
    if (t >= 0.0f && t < 11.0f) {
        int j = (int)t;
        if (j > 10) j = 10;
        float knot = (float)(j - 3) * 0.4f - 1.0f;
        float u  = (v - knot) * 2.5f;
        float um = 1.0f - u;
        float u2 = u * u, u3 = u2 * u;
        const float s6 = 1.0f / 6.0f;
        float w0 = um * um * um * s6;
        float w1 = (3.0f * u3 - 6.0f * u2 + 4.0f) * s6;
        float w2 = (-3.0f * u3 + 3.0f * u2 + 3.0f * u + 1.0f) * s6;
        float w3 = u3 * s6;
        int i0 = j - 3;
        if (i0 >= 0)               bs[i0]     = w0;
        if (i0 + 1 >= 0 && i0 < 7) bs[i0 + 1] = w1;
        if (i0 + 2 >= 0 && i0 < 6) bs[i0 + 2] = w2;
        if (i0 + 3 <= 7)           bs[i0 + 3] = w3;
    }
}

// ---- pre-kernel: fp32 weights -> bf16 B-frag streams (16x16x32 layout) ----
// wst[((nq*72 + S)*64 + lane)*8 + j] = ws[(nq*16 + (lane&15))*2304 + S*32 + (lane>>4)*8 + j]
// wbt[((nq*9  + s)*64 + lane)*8 + j] = wb[(nq*16 + (lane&15))*288  + s*32 + (lane>>4)*8 + j]
__global__ __launch_bounds__(256)
void cvt_swz_kernel(const float* __restrict__ ws, const float* __restrict__ wb,
                    unsigned short* __restrict__ wst, unsigned short* __restrict__ wbt) {
    int i = blockIdx.x * 256 + threadIdx.x;
    if (i < 147456) {
        int j = i & 7, l = (i >> 3) & 63, t = i >> 9;   // t 0..287
        int S = t % 72, nq = t / 72;
        int oc = nq * 16 + (l & 15);
        int k  = S * 32 + (l >> 4) * 8 + j;
        wst[i] = f2bf(ws[oc * 2304 + k]);
    } else {
        int i2 = i - 147456;
        if (i2 < 18432) {
            int j = i2 & 7, l = (i2 >> 3) & 63, t = i2 >> 9;  // t 0..35
            int s = t % 9, nq = t / 9;
            int oc = nq * 16 + (l & 15);
            int k  = s * 32 + (l >> 4) * 8 + j;
            wbt[i2] = f2bf(wb[oc * 288 + k]);
        }
    }
}

__global__ __launch_bounds__(512)
void kan_mfma_kernel(const float* __restrict__ x,
                     const float* __restrict__ sc,
                     const unsigned short* __restrict__ wst,
                     const unsigned short* __restrict__ wbt,
                     float* __restrict__ out) {
    __shared__ unsigned short smem[24832];   // 49664 B -> 3 blocks/CU (LDS cap)
    unsigned short* sb    = smem;            // [32][60][8] = 15360 ushorts
    unsigned short* patch = smem + 15360;    // [32][296]   = 9472 ushorts

    const int tid = threadIdx.x;
    const int bx  = blockIdx.x;              // 0..391
    const int b   = bx / 98;
    const int r   = bx - b * 98;
    const int ty  = r / 7;
    const int tx  = r - ty * 7;
    const int h0  = ty * 4, w0 = tx * 8;

    const int lane = tid & 63;
    const int wv   = tid >> 6;        // 0..7
    const int nq   = wv & 3;          // oc quarter (16 oc)
    const int mh   = wv >> 2;         // M half (16 rows)
    const int ml   = lane & 15;       // A row within half / B,C col (oc)
    const int kg   = lane >> 4;       // k-group 0..3 within k32 step
    const int m    = mh * 16 + ml;    // global pixel row 0..31
    const int py0  = m >> 3, px0 = m & 7;

    // ---- phase 1: batch 4 independent x loads, eval bases, store + scatter ----
    float vv[4];
    #pragma unroll
    for (int j = 0; j < 4; ++j) {
        int i = tid + j * 512;        // 0..2047
        float val = 0.0f;
        if (i < 1920) {
            int c  = i / 60;
            int hp = i - c * 60;
            int hy = hp / 10;
            int hx = hp - hy * 10;
            int hh = h0 + hy - 1, ww = w0 + hx - 1;
            if ((unsigned)hh < 56u && (unsigned)ww < 56u)
                val = x[((b * 32 + c) * 56 + hh) * 56 + ww];
        }
        vv[j] = val;
    }
    #pragma unroll
    for (int j = 0; j < 4; ++j) {
        int i = tid + j * 512;
        if (i < 1920) {
            int c  = i / 60;
            int hp = i - c * 60;
            int hy = hp / 10;
            int hx = hp - hy * 10;
            float bs[8];
            eval_bases(vv[j], bs);
            bf16x8 pk;
            #pragma unroll
            for (int j2 = 0; j2 < 8; ++j2) pk[j2] = (short)f2bf(bs[j2]);
            *reinterpret_cast<bf16x8*>(&sb[i * 8]) = pk;
            // scatter x into patch: halo (hy,hx) -> m=(hy-kh)*8+(hx-kw), k=c*9+kh*3+kw
            unsigned short xb = f2bf(vv[j]);
            #pragma unroll
            for (int kh = 0; kh < 3; ++kh) {
                int py = hy - kh;
                if ((unsigned)py < 4u) {
                    #pragma unroll
                    for (int kw = 0; kw < 3; ++kw) {
                        int px = hx - kw;
                        if ((unsigned)px < 8u)
                            patch[(py * 8 + px) * 296 + c * 9 + kh * 3 + kw] = xb;
                    }
                }
            }
        }
    }
    __syncthreads();

    // spline A offsets (ushort units): step s = 9g+u reads p = 4s + kg
    //   -> c = 4g + (4u+kg)/9, tap = (4u+kg)%9
    int aoff[9];
    #pragma unroll
    for (int u = 0; u < 9; ++u) {
        int tt  = 4 * u + kg;         // 0..35
        int dc  = tt / 9;
        int tap = tt - dc * 9;
        int kh  = tap / 3;
        int kw  = tap - kh * 3;
        aoff[u] = (dc * 60 + (py0 + kh) * 10 + (px0 + kw)) * 8;
    }

    f32x4 accS = {0.f, 0.f, 0.f, 0.f};
    f32x4 accB = {0.f, 0.f, 0.f, 0.f};

    // ---- spline GEMM: 72 k32-steps, full K per wave ----
    const unsigned short* bp = wst + (nq * 72 * 64 + lane) * 8;
    int cbase = 0;
    for (int g = 0; g < 8; ++g) {
        #pragma unroll
        for (int u = 0; u < 9; ++u) {
            bf16x8 a  = *reinterpret_cast<const bf16x8*>(&sb[cbase + aoff[u]]);
            bf16x8 bw = *reinterpret_cast<const bf16x8*>(bp + (g * 9 + u) * 512);
            accS = MFMA16(a, bw, accS);
        }
        cbase += 1920;                // 4 channels * 480 ushorts
    }

    // ---- base GEMM: 9 k32-steps ----
    {
        const unsigned short* ap  = patch + m * 296 + kg * 8;
        const unsigned short* bbp = wbt + (nq * 9 * 64 + lane) * 8;
        #pragma unroll
        for (int s = 0; s < 9; ++s) {
            bf16x8 a  = *reinterpret_cast<const bf16x8*>(ap + s * 32);
            bf16x8 bw = *reinterpret_cast<const bf16x8*>(bbp + s * 512);
            accB = MFMA16(a, bw, accB);
        }
    }

    // ---- epilogue: C/D row = (lane>>4)*4 + reg = pixel, col = ml = oc ----
    const int oc  = nq * 16 + ml;
    const float scv = sc[oc];
    const int rowb = mh * 16 + kg * 4;        // m of reg 0; regs span same py
    const int py   = rowb >> 3;
    const int pxb  = rowb & 7;                // 0 or 4
    float* ob = out + ((b * 64 + oc) * 56 + h0 + py) * 56 + w0 + pxb;
    f32x4 res;
    #pragma unroll
    for (int reg = 0; reg < 4; ++reg) {
        float bv = accB[reg];
        float si = bv / (1.0f + __expf(-bv));
        res[reg] = si + scv * accS[reg];
    }
    *reinterpret_cast<f32x4*>(ob) = res;
}

extern "C" void kernel_launch(void* const* d_in, const int* in_sizes, int n_in,
                              void* d_out, int out_size, void* d_ws, size_t ws_size,
                              hipStream_t stream) {
    const float* x  = (const float*)d_in[0];   // (4,32,56,56)
    const float* wb = (const float*)d_in[1];   // (64,32,3,3)
    const float* ws = (const float*)d_in[2];   // (64,288,8)
    const float* sc = (const float*)d_in[3];   // (64,)
    float* out = (float*)d_out;                // (4,64,56,56)

    unsigned short* wst = (unsigned short*)d_ws;   // 147456 bf16
    unsigned short* wbt = wst + 147456;            // 18432 bf16

    cvt_swz_kernel<<<648, 256, 0, stream>>>(ws, wb, wst, wbt);
    kan_mfma_kernel<<<392, 512, 0, stream>>>(x, sc, wst, wbt, out);
}